// Round 6
// baseline (268.162 us; speedup 1.0000x reference)
//
#include <hip/hip_runtime.h>

// RoIAlign forward, MI355X — round 6: persistent 8-item strips + 2-phase
// double-buffered pipeline (plain __syncthreads schedule; no inline asm).
//
// Shapes: features (4,256,200,200) fp32 NCHW, rois (512,5) fp32,
// out (512,256,7,7) fp32. OUT 7x7, sampling S=2, scale 0.25.
//
// Evidence so far: four structures converge to ~2.1-2.3 TB/s on this
// scattered gather (vs 6.6 TB/s contiguous). TLP (R1), in-flight batching
// (R3), DRAM-order sort (R4) gave at most +10-26%. Remaining levers:
//  - Cross-item L1 reuse: each block owns 8 CONSECUTIVE sorted nids
//    (same 8-channel slab, adjacent rois overlap footprints ~80-90%;
//    one footprint ~23KB of lines fits the 32KB L1) -> item i+1's loads
//    largely hit L1/L2 on lines item i just pulled.
//  - Latency overlap (guide T3 minimum 2-phase, m248-verified recipe):
//      issue(0); barrier; { issue(i+1); compute(i); barrier; }
//    Item i+1's global_load_lds fly DURING compute(i); the barrier's
//    vmcnt(0) drain then only waits for stragglers. Item i's data is
//    already resident+synced by the previous barrier, so no counted
//    vmcnt is needed (round 5's risky raw-barrier schedule deleted).
//
// Staging semantics identical to R3/R4: direct global->LDS width-16,
// fixed 8-slot rows (ys=s>>3, sx=s&7, 128B LDS row stride -> dst is
// linear wave-uniform-base + lane*16; lane0 is first-active whenever any
// lane is active since sx=0,ys=min -> base always from lane0's address).
//
// Footprint bound: roi_w = max((x2-x1)*0.25,1) <= 24 feat px; sample span
// <= 6.5/7*roi_w <= 22.3 -> fw,fh <= 25 = MAXF. x0 = xlo&~3 -> x-extent
// <= 28 -> nseg <= 7 16B segs/row. Plane stride 804 dw (==4 mod 32 -> the
// 8 compute cl-lanes hit distinct banks). OOB armor: clamp src to gend;
// clamped/garbage data lands only in slots compute never reads.

#define OH 7
#define OW 7
#define NSAMP 14
#define NB 4
#define CH 256
#define FH 200
#define FW 200
#define NR 512
#define CCH 8
#define MAXF 25
#define PSTR 804            // dwords per channel plane (201 slots); ==4 mod 32
#define BUFSTR (CCH * PSTR) // 6432 dwords per tile buffer
#define NIT 8               // items (rois) per block
#define GRID 2048           // GRID*NIT = 512*32 work items
#define BLK 256

// ---- pre-kernel: bitonic sort of roi indices by (batch, y, x) ----
__global__ __launch_bounds__(NR) void roi_sort(
    const float* __restrict__ rois, int* __restrict__ perm)
{
    __shared__ unsigned key[NR];
    const int t = threadIdx.x;
    {
        const int   b  = (int)rois[t * 5 + 0];
        const float x1 = rois[t * 5 + 1] * 0.25f;
        const float y1 = rois[t * 5 + 2] * 0.25f;
        const int qy = min(255, max(0, (int)y1));
        const int qx = min(255, max(0, (int)x1));
        key[t] = ((unsigned)b << 27) | ((unsigned)qy << 18)
               | ((unsigned)qx << 9) | (unsigned)t;
    }
    for (int k = 2; k <= NR; k <<= 1) {
        for (int j = k >> 1; j > 0; j >>= 1) {
            __syncthreads();
            const int ixj = t ^ j;
            if (ixj > t) {
                const unsigned a = key[t], c = key[ixj];
                const bool asc = ((t & k) == 0);
                if ((a > c) == asc) { key[t] = c; key[ixj] = a; }
            }
        }
    }
    __syncthreads();
    perm[t] = (int)(key[t] & (NR - 1u));
}

__global__ __launch_bounds__(BLK) void roialign_fwd(
    const float* __restrict__ feat,
    const float* __restrict__ rois,
    const int*   __restrict__ perm,
    float* __restrict__ out)
{
    __shared__ float tile[2 * BUFSTR];          // 51456 B, double-buffered
    __shared__ int   s_ilih[NIT][2][NSAMP];     // il | ih<<16
    __shared__ float s_w0[NIT][2][NSAMP];
    __shared__ float s_w1[NIT][2][NSAMP];
    __shared__ int4  s_item[NIT];               // {ylo, x0, fh|nseg<<8|b<<16, r}

    const int tid = threadIdx.x;
    const int bid = blockIdx.x;
    // XCD-chunked strips: XCD k (= bid&7 under round-robin dispatch) sweeps
    // nids [k*2048, (k+1)*2048) in order; strip = 8 consecutive nids, all in
    // the same chunk (512 % 8 == 0) and consecutive in sorted-roi order.
    const int nid_base = ((bid & 7) << 11) | ((bid >> 3) << 3);

    // ---- prologue: metadata for all 8 items, in parallel ----
    {
        const int j  = tid >> 5;                // item 0..7 (32-lane group)
        const int k  = tid & 31;
        const int kk = min(k, 27);
        const int axis = (kk >= NSAMP) ? 1 : 0;
        const int i    = kk - axis * NSAMP;
        const int r  = perm[(nid_base + j) & (NR - 1)];
        const int b  = (int)rois[r * 5 + 0];
        const float x1 = rois[r * 5 + 1] * 0.25f;
        const float y1 = rois[r * 5 + 2] * 0.25f;
        const float x2 = rois[r * 5 + 3] * 0.25f;
        const float y2 = rois[r * 5 + 4] * 0.25f;
        const float rw = fmaxf(x2 - x1, 1.0f);
        const float rh = fmaxf(y2 - y1, 1.0f);
        const float bsz   = (axis ? rw : rh) * (1.0f / OW);   // OW == OH
        const float start = axis ? x1 : y1;
        const float pos   = start + (i + 0.5f) * 0.5f * bsz;
        const float valid = (pos >= -1.0f && pos <= 200.0f) ? 1.0f : 0.0f;
        const float pc    = fminf(fmaxf(pos, 0.0f), 199.0f);
        const int   il    = (int)floorf(pc);
        const int   ih    = min(il + 1, 199);
        const float l     = pc - (float)il;
        if (k < 2 * NSAMP) {
            s_ilih[j][axis][i] = il | (ih << 16);
            s_w0[j][axis][i]   = (1.0f - l) * valid;
            s_w1[j][axis][i]   = l * valid;
        }
        // wave-uniform extremes via shuffles (group base within the wave)
        const int gb  = (tid & 63) & 32;
        const int ylo = __shfl(il, gb + 0, 64);   // axis0 i=0  lo
        const int yh  = __shfl(ih, gb + 13, 64);  // axis0 i=13 hi
        const int xlo = __shfl(il, gb + 14, 64);  // axis1 i=0  lo
        const int xh  = __shfl(ih, gb + 27, 64);  // axis1 i=13 hi
        if (k == 0) {
            const int fh   = min(yh - ylo + 1, MAXF);
            const int fw   = min(xh - xlo + 1, MAXF);
            const int x0   = xlo & ~3;
            const int nseg = (xlo - x0 + fw + 3) >> 2;       // <= 7
            s_item[j] = make_int4(ylo, x0, fh | (nseg << 8) | (b << 16), r);
        }
    }
    __syncthreads();

    const int lane = tid & 63;
    const int wave = tid >> 6;
    const float* gend = feat + (size_t)NB * CH * FH * FW - 4;

    // stage item j's footprint: async global->LDS, per wave 2 channel planes
    auto issue = [&](int j) {
        const int4 si  = s_item[j];
        const int ylo  = si.x, x0 = si.y;
        const int fh   = si.z & 0xff;
        const int nseg = (si.z >> 8) & 0xff;
        const int b    = si.z >> 16;
        const int c0   = ((nid_base + j) >> 9) << 3;          // chunk*8
        const float* fb =
            feat + ((size_t)((b * CH + c0) * FH + ylo)) * FW + x0;
        float* lbuf = tile + (j & 1) * BUFSTR;
        #pragma unroll
        for (int kp = 0; kp < 2; kp++) {
            const int c = (wave << 1) | kp;
            const float* gplane = fb + (size_t)c * (FH * FW);
            float* lplane = lbuf + c * PSTR;
            #pragma unroll
            for (int t = 0; t < 4; t++) {
                const int s  = (t << 6) + lane;
                const int ys = s >> 3, sx = s & 7;
                if ((ys < fh) & (sx < nseg)) {
                    const float* g = gplane + ys * FW + (sx << 2);
                    if (g > gend) g = gend;                   // OOB armor
                    __builtin_amdgcn_global_load_lds(
                        (const __attribute__((address_space(1))) void*)g,
                        (__attribute__((address_space(3))) void*)(lplane + (s << 2)),
                        16, 0, 0);
                }
            }
        }
    };

    auto compute = [&](int j) {
        const int4 si = s_item[j];
        const int ylo = si.x, x0 = si.y, r = si.w;
        const int c0  = ((nid_base + j) >> 9) << 3;
        const int cl  = tid & 7, slot = tid >> 3;
        const float* tc = tile + (j & 1) * BUFSTR + cl * PSTR;
        for (int bin = slot; bin < OH * OW; bin += 32) {
            const int ph = bin / OW;
            const int pw = bin - ph * OW;
            float acc = 0.0f;
            #pragma unroll
            for (int sy = 0; sy < 2; sy++) {
                const int gy  = ph * 2 + sy;
                const int pky = s_ilih[j][0][gy];
                const int rowl = ((pky & 0xffff) - ylo) << 5; // 32-dw rows
                const int rowh = ((pky >> 16)    - ylo) << 5;
                const float wy0 = s_w0[j][0][gy];
                const float wy1 = s_w1[j][0][gy];
                #pragma unroll
                for (int sx2 = 0; sx2 < 2; sx2++) {
                    const int gx  = pw * 2 + sx2;
                    const int pkx = s_ilih[j][1][gx];
                    const int ixl = (pkx & 0xffff) - x0;
                    const int ixh = (pkx >> 16)    - x0;
                    const float wx0 = s_w0[j][1][gx];
                    const float wx1 = s_w1[j][1][gx];
                    acc += wy0 * (wx0 * tc[rowl + ixl] + wx1 * tc[rowl + ixh])
                         + wy1 * (wx0 * tc[rowh + ixl] + wx1 * tc[rowh + ixh]);
                }
            }
            out[(size_t)(r * CH + c0 + cl) * (OH * OW) + bin] = acc * 0.25f;
        }
    };

    // ---- 2-phase pipeline (guide T3 minimum recipe, m248-verified):
    // issue(i+1)'s loads fly during compute(i); __syncthreads' vmcnt(0)
    // drain only catches stragglers. Item i's data was already resident
    // and synced by the previous barrier.
    issue(0);
    __syncthreads();
    #pragma unroll
    for (int i = 0; i < NIT - 1; i++) {
        issue(i + 1);        // -> buffer (i+1)&1, untouched by compute(i)
        compute(i);          // <- buffer i&1
        __syncthreads();
    }
    compute(NIT - 1);
}

extern "C" void kernel_launch(void* const* d_in, const int* in_sizes, int n_in,
                              void* d_out, int out_size, void* d_ws, size_t ws_size,
                              hipStream_t stream) {
    const float* feat = (const float*)d_in[0];
    const float* rois = (const float*)d_in[1];
    float* out = (float*)d_out;
    int* perm = (int*)d_ws;
    roi_sort<<<1, NR, 0, stream>>>(rois, perm);
    roialign_fwd<<<GRID, BLK, 0, stream>>>(feat, rois, perm, out);
}